// Round 13
// baseline (301.528 us; speedup 1.0000x reference)
//
#include <hip/hip_runtime.h>

#define S_LEN 512
#define HID   50
#define NB    16      // real batches per block (all 16 MFMA N-cols used)
#define NTHR  256     // 4 waves; wave w owns tiles {0-3},{4-6},{7-9},{10-12}

typedef _Float16 f16x8 __attribute__((ext_vector_type(8)));
typedef float    f32x4 __attribute__((ext_vector_type(4)));

#define LOG2E 1.44269504088896340736f

// TRANS ops via compiler intrinsics (NOT inline asm): round 9 proved the
// hazard recognizer must see the trans op class (asm version -> stale reads).
__device__ __forceinline__ float ex2(float a) {
#if __has_builtin(__builtin_amdgcn_exp2f)
    return __builtin_amdgcn_exp2f(a);
#else
    return __expf(0.69314718055994531f * a);
#endif
}
__device__ __forceinline__ float rcpf(float a) {
#if __has_builtin(__builtin_amdgcn_rcpf)
    return __builtin_amdgcn_rcpf(a);
#else
    return 1.0f / a;
#endif
}
// sigmoid(z) with a = -log2e*z folded into weights
__device__ __forceinline__ float sig_s(float a)  { return rcpf(1.0f + ex2(a)); }
// tanh(z) with a = 2*log2e*z folded into weights
__device__ __forceinline__ float tanh_s(float a) { return fmaf(-2.0f, rcpf(1.0f + ex2(a)), 1.0f); }

// half-index of h[unit u] for batch b (64 halfs/batch); XOR-swizzled 16B blocks
__device__ __forceinline__ int hIdx(int b, int u) {
    return b * 64 + ((((u >> 3) ^ (b & 7))) << 3) + (u & 7);
}

// MFMA LSTM round 13. R12 (13 waves x 1 tile, 236us rocprof) was lockstep-
// stalled: ~460cy/step idle because all 13 waves hit the barrier, then all
// issue 26 redundant ds_read_b128 (13x re-read of the same 2KB, ~208cy
// serialized) and wait ~120cy read latency with no out-of-phase wave to
// fill it. Fix: 4 waves x 3-4 tiles — ILP (3-4 independent MFMA+activation
// chains per wave) replaces useless TLP, read redundancy 13x->4x, barrier
// syncs 4 waves not 13. Worst-SIMD tile count (4) is unchanged — that is
// the issue floor. Math identical to verified R12 (K-folded x/bias in
// hext[50]/[51], gate rows pre-scaled by -log2e / +2log2e, intrinsic trans).
__global__ __launch_bounds__(NTHR, 1) void lstm_mfma_kernel(
    const float* __restrict__ x,      // [B, S] (I==1)
    const float* __restrict__ W_ih,   // [200, 1]
    const float* __restrict__ W_hh,   // [200, 50]
    const float* __restrict__ b_ih,   // [200]
    const float* __restrict__ b_hh,   // [200]
    const float* __restrict__ W_fc,   // [1, 50]
    const float* __restrict__ b_fc,   // [1]
    float* __restrict__ out)          // [B]
{
    const int blk  = blockIdx.x;
    const int tid  = threadIdx.x;     // 0..255
    const int wave = tid >> 6;        // 0..3
    const int lane = tid & 63;
    const int bcol = lane & 15;       // real batch column 0..15
    const int grp  = lane >> 4;       // 0..3

    __shared__ __align__(16) float    x_lds[S_LEN][NB];   // 32 KB
    __shared__ __align__(16) _Float16 h_lds[2][NB * 64];  // 4 KB

    // ---- zero h buffers (pads 52..63 must stay 0 forever) ----
    for (int i = tid; i < 2 * NB * 64; i += NTHR)
        (&h_lds[0][0])[i] = (_Float16)0.0f;
    __syncthreads();

    // ---- stage x transposed: x_lds[s][b] (16 lanes per batch row) ----
    {
        const int bb  = tid >> 4;     // 0..15
        const int ss0 = tid & 15;
        const float* xrow = x + (size_t)(blk * NB + bb) * S_LEN;
        #pragma unroll
        for (int i = 0; i < 32; ++i) {
            const int s = ss0 + 16 * i;
            x_lds[s][bb] = xrow[s];
        }
    }
    // seed K-extension slots: h[50] = x_0, h[51] = 1.0
    if (tid < NB) {
        h_lds[0][hIdx(tid, 50)] = (_Float16)x[(size_t)(blk * NB + tid) * S_LEN];
        h_lds[0][hIdx(tid, 51)] = (_Float16)1.0f;
        h_lds[1][hIdx(tid, 51)] = (_Float16)1.0f;
    }

    // tiles: wave0 -> 0..3, wave1 -> 4..6, wave2 -> 7..9, wave3 -> 10..12
    const int t0  = (wave == 0) ? 0 : (wave == 1) ? 4 : (wave == 2) ? 7 : 10;
    const int ntl = (wave == 0) ? 4 : 3;

    // A fragments (packed row = 4*unit+gate, extended K):
    //   k<50 -> W_hh[orow][k]; k==50 -> W_ih[orow]; k==51 -> bias; else 0
    //   rows pre-scaled by -log2e (i,f,o) / +2log2e (g)
    f16x8 afA[2], afB[2], afC[2], afD[2];
    auto load_tile = [&](int t, bool active, f16x8 (&af)[2]) __attribute__((always_inline)) {
        const int prow = 16 * t + (lane & 15);
        const int ua = prow >> 2, ga = prow & 3;
        const float sc = (ga == 2) ? (2.0f * LOG2E) : (-LOG2E);
        const int orow = ga * HID + ua;
        #pragma unroll
        for (int kc = 0; kc < 2; ++kc) {
            f16x8 fr;
            #pragma unroll
            for (int e = 0; e < 8; ++e) {
                const int k = 32 * kc + 8 * grp + e;
                float wv = 0.0f;
                if (active && ua < HID) {
                    if (k < HID)       wv = W_hh[orow * HID + k];
                    else if (k == 50)  wv = W_ih[orow];
                    else if (k == 51)  wv = b_ih[orow] + b_hh[orow];
                }
                fr[e] = (_Float16)(sc * wv);
            }
            af[kc] = fr;
        }
    };
    load_tile(t0 + 0, true,      afA);
    load_tile(t0 + 1, true,      afB);
    load_tile(t0 + 2, true,      afC);
    load_tile(t0 + 3, ntl == 4,  afD);

    // hoisted per-tile write index + guard (u=50/51 are the x/1.0 slots —
    // wr excludes them), and B-frag LDS offsets
    const int uA = 4 * (t0 + 0) + grp, uB = 4 * (t0 + 1) + grp;
    const int uC = 4 * (t0 + 2) + grp, uD = 4 * (t0 + 3) + grp;
    const bool wA = (uA < HID), wB = (uB < HID);
    const bool wC = (uC < HID), wD = (uD < HID) && (ntl == 4);
    const int iA = hIdx(bcol, uA < 64 ? uA : 0), iB = hIdx(bcol, uB < 64 ? uB : 0);
    const int iC = hIdx(bcol, uC < 64 ? uC : 0), iD = hIdx(bcol, uD < 64 ? uD : 0);
    const int off0 = bcol * 64 + ((grp ^ (bcol & 7)) << 3);
    const int off1 = bcol * 64 + (((4 + grp) ^ (bcol & 7)) << 3);
    const bool xfeed = (wave == 3) && (lane < NB);

    float cstA = 0.0f, cstB = 0.0f, cstC = 0.0f, cstD = 0.0f;

    __syncthreads();

    for (int s = 0; s < S_LEN; ++s) {
        const _Float16* hcur = h_lds[s & 1];
        _Float16*       hnxt = h_lds[(s & 1) ^ 1];

        const f16x8 bfr0 = *reinterpret_cast<const f16x8*>(hcur + off0);
        const f16x8 bfr1 = *reinterpret_cast<const f16x8*>(hcur + off1);

        auto do_tile = [&](const f16x8 (&af)[2], float& cst,
                           int widx, bool wr) __attribute__((always_inline)) {
            f32x4 acc = {0.0f, 0.0f, 0.0f, 0.0f};
            acc = __builtin_amdgcn_mfma_f32_16x16x32_f16(af[0], bfr0, acc, 0, 0, 0);
            acc = __builtin_amdgcn_mfma_f32_16x16x32_f16(af[1], bfr1, acc, 0, 0, 0);
            const float ig = sig_s(acc[0]);
            const float fg = sig_s(acc[1]);
            const float gg = tanh_s(acc[2]);
            const float og = sig_s(acc[3]);
            cst = fmaf(fg, cst, ig * gg);
            const float hv = og * tanh_s(cst * (2.0f * LOG2E));
            if (wr) hnxt[widx] = (_Float16)hv;
        };
        do_tile(afA, cstA, iA, wA);
        do_tile(afB, cstB, iB, wB);
        do_tile(afC, cstC, iC, wC);
        if (ntl == 4) do_tile(afD, cstD, iD, wD);

        // feed next step's x into the K-extension slot (wave 3: 3 tiles only)
        if (xfeed && s + 1 < S_LEN)
            hnxt[hIdx(lane, 50)] = (_Float16)x_lds[s + 1][lane];

        __syncthreads();
    }

    // final h is in h_lds[0] (step 511 wrote buffer 0)
    if (tid < NB) {
        const _Float16* hf = h_lds[0];
        float sum = b_fc[0];
        for (int uu = 0; uu < HID; ++uu)
            sum += W_fc[uu] * (float)hf[hIdx(tid, uu)];
        out[blk * NB + tid] = 1.0f / (1.0f + __expf(-sum));
    }
}

extern "C" void kernel_launch(void* const* d_in, const int* in_sizes, int n_in,
                              void* d_out, int out_size, void* d_ws, size_t ws_size,
                              hipStream_t stream) {
    const float* x    = (const float*)d_in[0];
    const float* W_ih = (const float*)d_in[1];
    const float* W_hh = (const float*)d_in[2];
    const float* b_ih = (const float*)d_in[3];
    const float* b_hh = (const float*)d_in[4];
    const float* W_fc = (const float*)d_in[5];
    const float* b_fc = (const float*)d_in[6];
    float* out = (float*)d_out;

    lstm_mfma_kernel<<<4096 / NB, NTHR, 0, stream>>>(x, W_ih, W_hh, b_ih, b_hh,
                                                     W_fc, b_fc, out);
}